// Round 5
// baseline (698.829 us; speedup 1.0000x reference)
//
#include <hip/hip_runtime.h>
#include <cstdint>
#include <cstddef>

typedef __bf16 bf16;
typedef __attribute__((ext_vector_type(8))) bf16  bf16x8;
typedef __attribute__((ext_vector_type(4))) bf16  bf16x4;
typedef __attribute__((ext_vector_type(4))) float f32x4;

// Problem constants
#define B_SZ   2
#define T_SZ   32
#define H_SZ   18
#define W_SZ   32
#define DIM    1024
#define NHEAD  16
#define HDIM   64
#define E3     3072                  // 3*NHEAD*HDIM
#define M_TOT  36864                 // B*T*H*W
#define T_STRIDE 576                 // H_SZ*W_SZ rows per t step
#define GK     1024                  // K of both GEMMs (compile-time)
#define NKT    16                    // GK / 64

// ---------------------------------------------------------------------------
// fp32 -> bf16 conversion (vectorized x4)
// ---------------------------------------------------------------------------
__global__ void taa_cvt_bf16(const float* __restrict__ s, bf16* __restrict__ d, int n4) {
    int i = blockIdx.x * 256 + threadIdx.x;
    if (i >= n4) return;
    float4 v = ((const float4*)s)[i];
    bf16x4 o;
    o.x = (bf16)v.x; o.y = (bf16)v.y; o.z = (bf16)v.z; o.w = (bf16)v.w;
    ((bf16x4*)d)[i] = o;
}

// ---------------------------------------------------------------------------
// async global->LDS 16B (wave-uniform base + lane*16 semantics)
// ---------------------------------------------------------------------------
__device__ __forceinline__ void async_copy_16(const bf16* g, bf16* l) {
    __builtin_amdgcn_global_load_lds((__attribute__((address_space(1))) void*)g,
                                     (__attribute__((address_space(3))) void*)l,
                                     16, 0, 0);
}

#define MFMA16(a, b, c) __builtin_amdgcn_mfma_f32_16x16x32_bf16((a), (b), (c), 0, 0, 0)

// ---------------------------------------------------------------------------
// C[M,N] = A[M,K] * B[N,K]^T, bf16 in, fp32 accumulate. 256x256 tile, BK=64,
// 512 threads = 8 waves (2M x 4N), each wave 128x64 output.
//
// K-tile schedule (round-5 revision): depth-1 prefetch into the OPPOSITE
// buffer, issued at tile START, drained at tile END (T14 issue-early /
// wait-late). Eliminates the mid-tile lgkmcnt(0)+barrier convoy that rounds
// 3/4 had (staging into the same-parity buffer required a full LDS drain
// before DMA could issue; both measured ~850-890 TF with ~55% idle).
//   [entry: buf=kt&1 data landed, waves synced]
//   stage kt+1 -> buf^1      // safe: buf^1's readers retired last tile,
//                            // barrier-separated at tile entry
//   24 ds_read_b128 + 64 MFMA  // plain loads; compiler streams with counted
//                              // lgkmcnt; reads overlap MFMA
//   lgkmcnt(0)  (free: all reads already consumed by MFMAs)
//   vmcnt(0)    (waits THIS tile's 8 DMAs, issued a full tile (~2500cy) ago;
//                DMA needs ~1200-1800cy -> residual stall small)
//   s_barrier   // ONE barrier per K-tile
//
// LDS: [2 dbuf][2 half][128][64] bf16 for A and B = 128 KiB total.
// Bank-conflict fix (T2): 16B-chunk XOR swizzle chunk ^= (row&7), applied on
// the pre-swizzled GLOBAL source of global_load_lds (dest stays linear) and
// identically on the ds_read side (row%8 == fr%8 for every fragment row).
// XCD-aware bijective blockIdx swizzle (grid % 8 == 0 for both GEMMs).
// ---------------------------------------------------------------------------
template<bool OUT_BF16>
__global__ __launch_bounds__(512, 2)
void taa_gemm256(const bf16* __restrict__ A, const bf16* __restrict__ Bm,
                 void* __restrict__ Cout, const float* __restrict__ bias, int N) {
    __shared__ __align__(16) bf16 sA[2][2][8192];   // [buf][half][128*64]
    __shared__ __align__(16) bf16 sB[2][2][8192];

    const int tid  = threadIdx.x;
    const int lane = tid & 63;
    const int wv   = tid >> 6;          // 0..7
    const int wm   = wv >> 2;           // 0..1 : wave rows  wm*128
    const int wn   = wv & 3;            // 0..3 : wave cols  wn*64
    const int fr   = lane & 15;
    const int fq   = lane >> 4;

    // XCD-aware bijective swizzle (nwg % 8 == 0 guaranteed by launch)
    const int ntn = N >> 8;
    const int nwg = gridDim.x;
    const int bid = blockIdx.x;
    const int swz = (bid & 7) * (nwg >> 3) + (bid >> 3);
    const int bm  = (swz / ntn) << 8;
    const int bn  = (swz % ntn) << 8;

    // staging: per issue, thread covers LDS element range [issue*4096 + tid*8, +8)
    // of a 16KB half-buffer (linear dest). Logical row = issue*64 + tid>>3,
    // source col chunk pre-swizzled: (tid&7) ^ (row&7).
    const int srow = tid >> 3;                          // 0..63
    const int scol = ((tid & 7) ^ (srow & 7)) << 3;     // element col in [0,64)
    const bf16* gA0 = A  + (size_t)(bm + srow) * GK + scol;
    const bf16* gB0 = Bm + (size_t)(bn + srow) * GK + scol;

    // per-lane swizzled k-chunk byte offsets for fragment ds_reads
    const int swx = (fr & 7) << 4;
    const int cs0 = (fq * 16) ^ swx;          // k-step 0
    const int cs1 = (64 + fq * 16) ^ swx;     // k-step 1

    f32x4 acc[2][2][4][2];                    // [ms][ns][i][j]
#pragma unroll
    for (int ms = 0; ms < 2; ms++)
#pragma unroll
        for (int ns = 0; ns < 2; ns++)
#pragma unroll
            for (int i = 0; i < 4; i++)
#pragma unroll
                for (int j = 0; j < 2; j++)
                    acc[ms][ns][i][j] = (f32x4){0.f, 0.f, 0.f, 0.f};

    // one stage() = one 16KB half-tile = 2 global_load_lds per wave
    auto stage = [&](const bf16* g0, bf16* lbase, int h, int kt) {
        const bf16* g = g0 + (size_t)(h * 128) * GK + kt * 64;
        async_copy_16(g,                    lbase + h * 8192 + tid * 8);
        async_copy_16(g + (size_t)64 * GK,  lbase + h * 8192 + 4096 + tid * 8);
    };

    // ---- prologue: stage kt=0 -> buf0, drain, sync ----
    stage(gB0, &sB[0][0][0], 0, 0); stage(gB0, &sB[0][0][0], 1, 0);
    stage(gA0, &sA[0][0][0], 0, 0); stage(gA0, &sA[0][0][0], 1, 0);
    asm volatile("s_waitcnt vmcnt(0)" ::: "memory");
    __builtin_amdgcn_s_barrier();
    asm volatile("" ::: "memory");

#pragma unroll 2
    for (int kt = 0; kt < NKT; ++kt) {
        const int buf = kt & 1;
        const char* ab = (const char*)&sA[buf][wm][0] + fr * 128;
        const char* bb = (const char*)&sB[buf][wn >> 1][0] + ((wn & 1) * 64 + fr) * 128;

        // ---- issue next-tile staging FIRST, into the buffer NOT being read.
        // buf^1's last readers were tile kt-1; they retired (lgkmcnt(0)) before
        // the entry barrier -> no drain needed here.
        if (kt + 1 < NKT) {
            stage(gB0, &sB[buf ^ 1][0][0], 0, kt + 1);
            stage(gB0, &sB[buf ^ 1][0][0], 1, kt + 1);
            stage(gA0, &sA[buf ^ 1][0][0], 0, kt + 1);
            stage(gA0, &sA[buf ^ 1][0][0], 1, kt + 1);
        }

        // ---- fragment reads (compiler streams them under the MFMAs) ----
        bf16x8 af[4][2];    // A half ms=0
        bf16x8 ag[4][2];    // A half ms=1
        bf16x8 bf0[2][2];   // B ns=0
        bf16x8 bf1[2][2];   // B ns=1

        af[0][0] = *(const bf16x8*)(ab + cs0);
        af[0][1] = *(const bf16x8*)(ab + cs1);
#pragma unroll
        for (int j = 0; j < 2; j++) {
            bf0[j][0] = *(const bf16x8*)(bb + j * 2048 + cs0);
            bf0[j][1] = *(const bf16x8*)(bb + j * 2048 + cs1);
        }
#pragma unroll
        for (int i = 1; i < 4; i++) {
            af[i][0] = *(const bf16x8*)(ab + i * 2048 + cs0);
            af[i][1] = *(const bf16x8*)(ab + i * 2048 + cs1);
        }
#pragma unroll
        for (int j = 0; j < 2; j++) {
            bf1[j][0] = *(const bf16x8*)(bb + 4096 + j * 2048 + cs0);
            bf1[j][1] = *(const bf16x8*)(bb + 4096 + j * 2048 + cs1);
        }
#pragma unroll
        for (int i = 0; i < 4; i++) {
            ag[i][0] = *(const bf16x8*)(ab + 8192 + i * 2048 + cs0);
            ag[i][1] = *(const bf16x8*)(ab + 8192 + i * 2048 + cs1);
        }

        __builtin_amdgcn_s_setprio(1);
#pragma unroll
        for (int i = 0; i < 4; i++)
#pragma unroll
            for (int j = 0; j < 2; j++) {
                acc[0][0][i][j] = MFMA16(af[i][0], bf0[j][0], acc[0][0][i][j]);
                acc[0][0][i][j] = MFMA16(af[i][1], bf0[j][1], acc[0][0][i][j]);
            }
#pragma unroll
        for (int i = 0; i < 4; i++)
#pragma unroll
            for (int j = 0; j < 2; j++) {
                acc[0][1][i][j] = MFMA16(af[i][0], bf1[j][0], acc[0][1][i][j]);
                acc[0][1][i][j] = MFMA16(af[i][1], bf1[j][1], acc[0][1][i][j]);
            }
#pragma unroll
        for (int i = 0; i < 4; i++)
#pragma unroll
            for (int j = 0; j < 2; j++) {
                acc[1][1][i][j] = MFMA16(ag[i][0], bf1[j][0], acc[1][1][i][j]);
                acc[1][1][i][j] = MFMA16(ag[i][1], bf1[j][1], acc[1][1][i][j]);
            }
#pragma unroll
        for (int i = 0; i < 4; i++)
#pragma unroll
            for (int j = 0; j < 2; j++) {
                acc[1][0][i][j] = MFMA16(ag[i][0], bf0[j][0], acc[1][0][i][j]);
                acc[1][0][i][j] = MFMA16(ag[i][1], bf0[j][1], acc[1][0][i][j]);
            }
        __builtin_amdgcn_s_setprio(0);

        // reads all retired (consumed by MFMAs -> lgkmcnt(0) is ~free);
        // this tile's 8 DMAs (issued at tile start) must have landed.
        asm volatile("s_waitcnt lgkmcnt(0) vmcnt(0)" ::: "memory");
        __builtin_amdgcn_s_barrier();
        asm volatile("" ::: "memory");
    }

    // ---- epilogue: C/D layout col=lane&15, row=(lane>>4)*4+reg ----
    if constexpr (OUT_BF16) {
        bf16* C = (bf16*)Cout;
#pragma unroll
        for (int ms = 0; ms < 2; ms++)
#pragma unroll
            for (int ns = 0; ns < 2; ns++)
#pragma unroll
                for (int i = 0; i < 4; i++)
#pragma unroll
                    for (int j = 0; j < 2; j++)
#pragma unroll
                        for (int r = 0; r < 4; r++) {
                            const int row = bm + wm * 128 + ms * 64 + i * 16 + fq * 4 + r;
                            const int col = bn + wn * 64 + ns * 32 + j * 16 + fr;
                            C[(size_t)row * N + col] = (bf16)acc[ms][ns][i][j][r];
                        }
    } else {
        float* C = (float*)Cout;
#pragma unroll
        for (int ms = 0; ms < 2; ms++)
#pragma unroll
            for (int ns = 0; ns < 2; ns++)
#pragma unroll
                for (int i = 0; i < 4; i++)
#pragma unroll
                    for (int j = 0; j < 2; j++)
#pragma unroll
                        for (int r = 0; r < 4; r++) {
                            const int row = bm + wm * 128 + ms * 64 + i * 16 + fq * 4 + r;
                            const int col = bn + wn * 64 + ns * 32 + j * 16 + fr;
                            C[(size_t)row * N + col] = acc[ms][ns][i][j][r] + bias[col];
                        }
    }
}

// ---------------------------------------------------------------------------
// MFMA attention: one 64-thread wave per (n, head). T=32, D=64. (unchanged)
// ---------------------------------------------------------------------------
__global__ __launch_bounds__(64)
void taa_attn_mfma(const bf16* __restrict__ qkv, bf16* __restrict__ o) {
    __shared__ __align__(16) bf16 sQ[32 * 72];   // stride 72: +8 pad -> 2-way banks
    __shared__ __align__(16) bf16 sK[32 * 72];
    __shared__ __align__(16) bf16 sVt[64 * 40];  // V^T [d][t], stride 40
    __shared__ __align__(16) bf16 sP[32 * 40];   // P   [tq][tk], stride 40

    const int lane = threadIdx.x;
    const int bid  = blockIdx.x;        // n*16 + head
    const int head = bid & 15;
    const int n    = bid >> 4;          // (b*18 + h)*32 + w
    const int w_sp = n & 31;
    const int h_sp = (n >> 5) % 18;
    const int b    = n / (18 * 32);
    const int m0   = b * 18432 + h_sp * 32 + w_sp;   // row for t=0

    // ---- load Q,K (RoPE) and V (transposed) into LDS ----
    {
        const int tl = lane >> 3;          // 0..7
        const int dl = (lane & 7) * 8;     // 0..56
#pragma unroll
        for (int it = 0; it < 4; ++it) {
            const int t = it * 8 + tl;
            const size_t rb = (size_t)(m0 + t * T_STRIDE) * E3 + head * 64 + dl;
            bf16x8 q8 = *(const bf16x8*)(qkv + rb);
            bf16x8 k8 = *(const bf16x8*)(qkv + rb + 1024);
            bf16x8 v8 = *(const bf16x8*)(qkv + rb + 2048);
            float qf[8], kf[8];
#pragma unroll
            for (int j = 0; j < 8; j++) { qf[j] = (float)q8[j]; kf[j] = (float)k8[j]; }
            if (dl < 32) {
#pragma unroll
                for (int p = 0; p < 4; p++) {
                    const int fi = dl / 2 + p;                   // pair 0..15
                    float freq = exp2f(-(float)fi * 0.830482024f); // 10000^(-fi/16)
                    float ang  = (float)t * freq;
                    float s, c;
                    __sincosf(ang, &s, &c);
                    float a = qf[2 * p], bb = qf[2 * p + 1];
                    qf[2 * p]     = a * c - bb * s;
                    qf[2 * p + 1] = bb * c + a * s;
                    a = kf[2 * p]; bb = kf[2 * p + 1];
                    kf[2 * p]     = a * c - bb * s;
                    kf[2 * p + 1] = bb * c + a * s;
                }
            }
            bf16x8 qo, ko;
#pragma unroll
            for (int j = 0; j < 8; j++) { qo[j] = (bf16)qf[j]; ko[j] = (bf16)kf[j]; }
            *(bf16x8*)&sQ[t * 72 + dl] = qo;
            *(bf16x8*)&sK[t * 72 + dl] = ko;
#pragma unroll
            for (int j = 0; j < 8; j++) sVt[(dl + j) * 40 + t] = v8[j];
        }
    }
    __syncthreads();

    const int fr = lane & 15;
    const int fq = lane >> 4;            // 0..3

    // ---- S = Q K^T, 2x2 tiles, K=64 ----
    f32x4 S[2][2];
#pragma unroll
    for (int mt = 0; mt < 2; mt++)
#pragma unroll
        for (int nt = 0; nt < 2; nt++) S[mt][nt] = (f32x4){0.f, 0.f, 0.f, 0.f};

    bf16x8 kb0[2], kb1[2];
#pragma unroll
    for (int nt = 0; nt < 2; nt++) {
        kb0[nt] = *(const bf16x8*)&sK[(nt * 16 + fr) * 72 + fq * 8];
        kb1[nt] = *(const bf16x8*)&sK[(nt * 16 + fr) * 72 + 32 + fq * 8];
    }
#pragma unroll
    for (int mt = 0; mt < 2; mt++) {
        bf16x8 a0 = *(const bf16x8*)&sQ[(mt * 16 + fr) * 72 + fq * 8];
        bf16x8 a1 = *(const bf16x8*)&sQ[(mt * 16 + fr) * 72 + 32 + fq * 8];
#pragma unroll
        for (int nt = 0; nt < 2; nt++) {
            S[mt][nt] = __builtin_amdgcn_mfma_f32_16x16x32_bf16(a0, kb0[nt], S[mt][nt], 0, 0, 0);
            S[mt][nt] = __builtin_amdgcn_mfma_f32_16x16x32_bf16(a1, kb1[nt], S[mt][nt], 0, 0, 0);
        }
    }

    // ---- causal softmax in registers ----
    float P[2][2][4];
#pragma unroll
    for (int mt = 0; mt < 2; mt++) {
#pragma unroll
        for (int r = 0; r < 4; r++) {
            const int row = mt * 16 + fq * 4 + r;
            float s0 = S[mt][0][r] * 0.125f;
            float s1 = S[mt][1][r] * 0.125f;
            if (fr > row)      s0 = -1e30f;
            if (16 + fr > row) s1 = -1e30f;
            float mx = fmaxf(s0, s1);
#pragma unroll
            for (int mk = 1; mk <= 8; mk <<= 1) mx = fmaxf(mx, __shfl_xor(mx, mk, 64));
            float e0 = __expf(s0 - mx);
            float e1 = __expf(s1 - mx);
            float sm = e0 + e1;
#pragma unroll
            for (int mk = 1; mk <= 8; mk <<= 1) sm += __shfl_xor(sm, mk, 64);
            float inv = 1.0f / sm;
            P[mt][0][r] = e0 * inv;
            P[mt][1][r] = e1 * inv;
        }
    }

    // ---- P -> LDS (C-layout scatter), read back in A-layout ----
#pragma unroll
    for (int mt = 0; mt < 2; mt++)
#pragma unroll
        for (int nt = 0; nt < 2; nt++)
#pragma unroll
            for (int r = 0; r < 4; r++)
                sP[(mt * 16 + fq * 4 + r) * 40 + nt * 16 + fr] = (bf16)P[mt][nt][r];
    __syncthreads();

    // ---- O = P V, 2x4 tiles, K=32 ----
    f32x4 O[2][4];
#pragma unroll
    for (int mt = 0; mt < 2; mt++)
#pragma unroll
        for (int dt = 0; dt < 4; dt++) O[mt][dt] = (f32x4){0.f, 0.f, 0.f, 0.f};
#pragma unroll
    for (int mt = 0; mt < 2; mt++) {
        bf16x8 a = *(const bf16x8*)&sP[(mt * 16 + fr) * 40 + fq * 8];
#pragma unroll
        for (int dt = 0; dt < 4; dt++) {
            bf16x8 bv = *(const bf16x8*)&sVt[(dt * 16 + fr) * 40 + fq * 8];
            O[mt][dt] = __builtin_amdgcn_mfma_f32_16x16x32_bf16(a, bv, O[mt][dt], 0, 0, 0);
        }
    }

    // ---- write O: row t = mt*16+fq*4+r, col d = dt*16+fr ----
#pragma unroll
    for (int mt = 0; mt < 2; mt++)
#pragma unroll
        for (int dt = 0; dt < 4; dt++)
#pragma unroll
            for (int r = 0; r < 4; r++) {
                const int t = mt * 16 + fq * 4 + r;
                const int d = dt * 16 + fr;
                o[(size_t)(m0 + t * T_STRIDE) * DIM + head * 64 + d] = (bf16)O[mt][dt][r];
            }
}

// ---------------------------------------------------------------------------
extern "C" void kernel_launch(void* const* d_in, const int* in_sizes, int n_in,
                              void* d_out, int out_size, void* d_ws, size_t ws_size,
                              hipStream_t stream) {
    const float* x     = (const float*)d_in[0];
    const float* w_qkv = (const float*)d_in[1];
    const float* w_out = (const float*)d_in[2];
    const float* b_out = (const float*)d_in[3];

    char* ws = (char*)d_ws;
    // workspace layout (bytes)
    bf16* x_b    = (bf16*)(ws + 0);            //  75,497,472  x as bf16
    bf16* wqkv_b = (bf16*)(ws + 75497472);     //   6,291,456
    bf16* wout_b = (bf16*)(ws + 81788928);     //   2,097,152
    bf16* qkv_b  = (bf16*)(ws + 83886080);     // 226,492,416  qkv [M,3072] bf16
    bf16* o_b    = (bf16*)(ws + 310378496);    //  75,497,472  o   [M,1024] bf16
                                               // total 385,875,968

    // convert inputs to bf16
    taa_cvt_bf16<<<(M_TOT * DIM / 4 + 255) / 256, 256, 0, stream>>>(x, x_b, M_TOT * DIM / 4);
    taa_cvt_bf16<<<(E3 * DIM / 4 + 255) / 256, 256, 0, stream>>>(w_qkv, wqkv_b, E3 * DIM / 4);
    taa_cvt_bf16<<<(DIM * DIM / 4 + 255) / 256, 256, 0, stream>>>(w_out, wout_b, DIM * DIM / 4);

    // QKV projection: [36864,3072] = x_b[36864,1024] * wqkv_b[3072,1024]^T
    taa_gemm256<true><<<dim3((M_TOT / 256) * (E3 / 256)), 512, 0, stream>>>(
        x_b, wqkv_b, (void*)qkv_b, nullptr, E3);

    // MFMA attention: one wave per (n, head)
    taa_attn_mfma<<<1152 * 16, 64, 0, stream>>>(qkv_b, o_b);

    // output projection: d_out[36864,1024] = o_b * wout_b^T + b_out
    taa_gemm256<false><<<dim3((M_TOT / 256) * (DIM / 256)), 512, 0, stream>>>(
        o_b, wout_b, d_out, b_out, DIM);
}

// Round 6
// 695.076 us; speedup vs baseline: 1.0054x; 1.0054x over previous
//
#include <hip/hip_runtime.h>
#include <cstdint>
#include <cstddef>

typedef __bf16 bf16;
typedef __attribute__((ext_vector_type(8))) bf16  bf16x8;
typedef __attribute__((ext_vector_type(4))) bf16  bf16x4;
typedef __attribute__((ext_vector_type(4))) float f32x4;

// Problem constants
#define B_SZ   2
#define T_SZ   32
#define H_SZ   18
#define W_SZ   32
#define DIM    1024
#define NHEAD  16
#define HDIM   64
#define E3     3072                  // 3*NHEAD*HDIM
#define M_TOT  36864                 // B*T*H*W
#define T_STRIDE 576                 // H_SZ*W_SZ rows per t step
#define GK     1024                  // K of both GEMMs (compile-time)
#define NKT    16                    // GK / 64

// ---------------------------------------------------------------------------
// fp32 -> bf16 conversion (vectorized x4)
// ---------------------------------------------------------------------------
__global__ void taa_cvt_bf16(const float* __restrict__ s, bf16* __restrict__ d, int n4) {
    int i = blockIdx.x * 256 + threadIdx.x;
    if (i >= n4) return;
    float4 v = ((const float4*)s)[i];
    bf16x4 o;
    o.x = (bf16)v.x; o.y = (bf16)v.y; o.z = (bf16)v.z; o.w = (bf16)v.w;
    ((bf16x4*)d)[i] = o;
}

// ---------------------------------------------------------------------------
// async global->LDS 16B (wave-uniform base + lane*16 semantics)
// ---------------------------------------------------------------------------
__device__ __forceinline__ void async_copy_16(const bf16* g, bf16* l) {
    __builtin_amdgcn_global_load_lds((__attribute__((address_space(1))) void*)g,
                                     (__attribute__((address_space(3))) void*)l,
                                     16, 0, 0);
}

#define MFMA16(a, b, c) __builtin_amdgcn_mfma_f32_16x16x32_bf16((a), (b), (c), 0, 0, 0)

// ---------------------------------------------------------------------------
// C[M,N] = A[M,K] * B[N,K]^T, bf16 in, fp32 accumulate. 256x256 tile, BK=64,
// 512 threads = 8 waves (2M x 4N), each wave 128x64 output.
// Round-5 schedule (kept as-is; equal-best 262us / 37% MfmaUtil):
//   stage kt+1 -> buf^1 at tile start; 24 ds_reads + 64 MFMA streamed;
//   lgkmcnt(0)+vmcnt(0)+one barrier at tile end.
// LDS: [2 dbuf][2 half][128][64] bf16 for A and B = 128 KiB total.
// T2 16B-chunk XOR swizzle on staging source + ds_read side; XCD-aware
// bijective blockIdx swizzle (grid % 8 == 0 for both GEMMs).
// ---------------------------------------------------------------------------
template<bool OUT_BF16>
__global__ __launch_bounds__(512, 2)
void taa_gemm256(const bf16* __restrict__ A, const bf16* __restrict__ Bm,
                 void* __restrict__ Cout, const float* __restrict__ bias, int N) {
    __shared__ __align__(16) bf16 sA[2][2][8192];   // [buf][half][128*64]
    __shared__ __align__(16) bf16 sB[2][2][8192];

    const int tid  = threadIdx.x;
    const int lane = tid & 63;
    const int wv   = tid >> 6;          // 0..7
    const int wm   = wv >> 2;           // 0..1 : wave rows  wm*128
    const int wn   = wv & 3;            // 0..3 : wave cols  wn*64
    const int fr   = lane & 15;
    const int fq   = lane >> 4;

    // XCD-aware bijective swizzle (nwg % 8 == 0 guaranteed by launch)
    const int ntn = N >> 8;
    const int nwg = gridDim.x;
    const int bid = blockIdx.x;
    const int swz = (bid & 7) * (nwg >> 3) + (bid >> 3);
    const int bm  = (swz / ntn) << 8;
    const int bn  = (swz % ntn) << 8;

    // staging: per issue, thread covers LDS element range [issue*4096 + tid*8, +8)
    // of a 16KB half-buffer (linear dest). Logical row = issue*64 + tid>>3,
    // source col chunk pre-swizzled: (tid&7) ^ (row&7).
    const int srow = tid >> 3;                          // 0..63
    const int scol = ((tid & 7) ^ (srow & 7)) << 3;     // element col in [0,64)
    const bf16* gA0 = A  + (size_t)(bm + srow) * GK + scol;
    const bf16* gB0 = Bm + (size_t)(bn + srow) * GK + scol;

    // per-lane swizzled k-chunk byte offsets for fragment ds_reads
    const int swx = (fr & 7) << 4;
    const int cs0 = (fq * 16) ^ swx;          // k-step 0
    const int cs1 = (64 + fq * 16) ^ swx;     // k-step 1

    f32x4 acc[2][2][4][2];                    // [ms][ns][i][j]
#pragma unroll
    for (int ms = 0; ms < 2; ms++)
#pragma unroll
        for (int ns = 0; ns < 2; ns++)
#pragma unroll
            for (int i = 0; i < 4; i++)
#pragma unroll
                for (int j = 0; j < 2; j++)
                    acc[ms][ns][i][j] = (f32x4){0.f, 0.f, 0.f, 0.f};

    // one stage() = one 16KB half-tile = 2 global_load_lds per wave
    auto stage = [&](const bf16* g0, bf16* lbase, int h, int kt) {
        const bf16* g = g0 + (size_t)(h * 128) * GK + kt * 64;
        async_copy_16(g,                    lbase + h * 8192 + tid * 8);
        async_copy_16(g + (size_t)64 * GK,  lbase + h * 8192 + 4096 + tid * 8);
    };

    // ---- prologue: stage kt=0 -> buf0, drain, sync ----
    stage(gB0, &sB[0][0][0], 0, 0); stage(gB0, &sB[0][0][0], 1, 0);
    stage(gA0, &sA[0][0][0], 0, 0); stage(gA0, &sA[0][0][0], 1, 0);
    asm volatile("s_waitcnt vmcnt(0)" ::: "memory");
    __builtin_amdgcn_s_barrier();
    asm volatile("" ::: "memory");

#pragma unroll 2
    for (int kt = 0; kt < NKT; ++kt) {
        const int buf = kt & 1;
        const char* ab = (const char*)&sA[buf][wm][0] + fr * 128;
        const char* bb = (const char*)&sB[buf][wn >> 1][0] + ((wn & 1) * 64 + fr) * 128;

        // ---- issue next-tile staging FIRST, into the buffer NOT being read.
        if (kt + 1 < NKT) {
            stage(gB0, &sB[buf ^ 1][0][0], 0, kt + 1);
            stage(gB0, &sB[buf ^ 1][0][0], 1, kt + 1);
            stage(gA0, &sA[buf ^ 1][0][0], 0, kt + 1);
            stage(gA0, &sA[buf ^ 1][0][0], 1, kt + 1);
        }

        // ---- fragment reads (compiler streams them under the MFMAs) ----
        bf16x8 af[4][2];    // A half ms=0
        bf16x8 ag[4][2];    // A half ms=1
        bf16x8 bf0[2][2];   // B ns=0
        bf16x8 bf1[2][2];   // B ns=1

        af[0][0] = *(const bf16x8*)(ab + cs0);
        af[0][1] = *(const bf16x8*)(ab + cs1);
#pragma unroll
        for (int j = 0; j < 2; j++) {
            bf0[j][0] = *(const bf16x8*)(bb + j * 2048 + cs0);
            bf0[j][1] = *(const bf16x8*)(bb + j * 2048 + cs1);
        }
#pragma unroll
        for (int i = 1; i < 4; i++) {
            af[i][0] = *(const bf16x8*)(ab + i * 2048 + cs0);
            af[i][1] = *(const bf16x8*)(ab + i * 2048 + cs1);
        }
#pragma unroll
        for (int j = 0; j < 2; j++) {
            bf1[j][0] = *(const bf16x8*)(bb + 4096 + j * 2048 + cs0);
            bf1[j][1] = *(const bf16x8*)(bb + 4096 + j * 2048 + cs1);
        }
#pragma unroll
        for (int i = 0; i < 4; i++) {
            ag[i][0] = *(const bf16x8*)(ab + 8192 + i * 2048 + cs0);
            ag[i][1] = *(const bf16x8*)(ab + 8192 + i * 2048 + cs1);
        }

        __builtin_amdgcn_s_setprio(1);
#pragma unroll
        for (int i = 0; i < 4; i++)
#pragma unroll
            for (int j = 0; j < 2; j++) {
                acc[0][0][i][j] = MFMA16(af[i][0], bf0[j][0], acc[0][0][i][j]);
                acc[0][0][i][j] = MFMA16(af[i][1], bf0[j][1], acc[0][0][i][j]);
            }
#pragma unroll
        for (int i = 0; i < 4; i++)
#pragma unroll
            for (int j = 0; j < 2; j++) {
                acc[0][1][i][j] = MFMA16(af[i][0], bf1[j][0], acc[0][1][i][j]);
                acc[0][1][i][j] = MFMA16(af[i][1], bf1[j][1], acc[0][1][i][j]);
            }
#pragma unroll
        for (int i = 0; i < 4; i++)
#pragma unroll
            for (int j = 0; j < 2; j++) {
                acc[1][1][i][j] = MFMA16(ag[i][0], bf1[j][0], acc[1][1][i][j]);
                acc[1][1][i][j] = MFMA16(ag[i][1], bf1[j][1], acc[1][1][i][j]);
            }
#pragma unroll
        for (int i = 0; i < 4; i++)
#pragma unroll
            for (int j = 0; j < 2; j++) {
                acc[1][0][i][j] = MFMA16(ag[i][0], bf0[j][0], acc[1][0][i][j]);
                acc[1][0][i][j] = MFMA16(ag[i][1], bf0[j][1], acc[1][0][i][j]);
            }
        __builtin_amdgcn_s_setprio(0);

        asm volatile("s_waitcnt lgkmcnt(0) vmcnt(0)" ::: "memory");
        __builtin_amdgcn_s_barrier();
        asm volatile("" ::: "memory");
    }

    // ---- epilogue: C/D layout col=lane&15, row=(lane>>4)*4+reg ----
    if constexpr (OUT_BF16) {
        bf16* C = (bf16*)Cout;
#pragma unroll
        for (int ms = 0; ms < 2; ms++)
#pragma unroll
            for (int ns = 0; ns < 2; ns++)
#pragma unroll
                for (int i = 0; i < 4; i++)
#pragma unroll
                    for (int j = 0; j < 2; j++)
#pragma unroll
                        for (int r = 0; r < 4; r++) {
                            const int row = bm + wm * 128 + ms * 64 + i * 16 + fq * 4 + r;
                            const int col = bn + wn * 64 + ns * 32 + j * 16 + fr;
                            C[(size_t)row * N + col] = (bf16)acc[ms][ns][i][j][r];
                        }
    } else {
        float* C = (float*)Cout;
#pragma unroll
        for (int ms = 0; ms < 2; ms++)
#pragma unroll
            for (int ns = 0; ns < 2; ns++)
#pragma unroll
                for (int i = 0; i < 4; i++)
#pragma unroll
                    for (int j = 0; j < 2; j++)
#pragma unroll
                        for (int r = 0; r < 4; r++) {
                            const int row = bm + wm * 128 + ms * 64 + i * 16 + fq * 4 + r;
                            const int col = bn + wn * 64 + ns * 32 + j * 16 + fr;
                            C[(size_t)row * N + col] = acc[ms][ns][i][j][r] + bias[col];
                        }
    }
}

// ---------------------------------------------------------------------------
// MFMA attention, round-6 revision: TWO waves per block (128 threads), one
// (n, head) per block. Wave wv owns query-row half mt=wv (16 rows); K/V/Q
// loads + RoPE are cooperative across all 128 threads. P's LDS is ALIASED
// onto sQ (Q is dead after the S MFMAs; one __syncthreads guards the
// overwrite). Per-block LDS 16.9 KB -> 14.0 KB and 1 wave -> 2 waves:
// occupancy 9 blocks/CU = 2.25 waves/SIMD -> 11 blocks/CU = 5.5 waves/SIMD.
// P scatter/read rows are wave-local (rows mt*16..mt*16+15), so PV needs no
// extra barrier.
// ---------------------------------------------------------------------------
__global__ __launch_bounds__(128)
void taa_attn_mfma(const bf16* __restrict__ qkv, bf16* __restrict__ o) {
    __shared__ __align__(16) bf16 sQ[32 * 72];   // stride 72; reused as sP [32][40]
    __shared__ __align__(16) bf16 sK[32 * 72];
    __shared__ __align__(16) bf16 sVt[64 * 40];  // V^T [d][t], stride 40

    const int tid  = threadIdx.x;
    const int lane = tid & 63;
    const int wv   = tid >> 6;          // 0..1 : query-row half (mt)
    const int bid  = blockIdx.x;        // n*16 + head
    const int head = bid & 15;
    const int n    = bid >> 4;          // (b*18 + h)*32 + w
    const int w_sp = n & 31;
    const int h_sp = (n >> 5) % 18;
    const int b    = n / (18 * 32);
    const int m0   = b * 18432 + h_sp * 32 + w_sp;   // row for t=0

    // ---- cooperative load of Q,K (RoPE) and V (transposed) into LDS ----
    {
        const int tl = tid >> 3;           // 0..15
        const int dl = (tid & 7) * 8;      // 0..56
#pragma unroll
        for (int it = 0; it < 2; ++it) {
            const int t = it * 16 + tl;
            const size_t rb = (size_t)(m0 + t * T_STRIDE) * E3 + head * 64 + dl;
            bf16x8 q8 = *(const bf16x8*)(qkv + rb);
            bf16x8 k8 = *(const bf16x8*)(qkv + rb + 1024);
            bf16x8 v8 = *(const bf16x8*)(qkv + rb + 2048);
            float qf[8], kf[8];
#pragma unroll
            for (int j = 0; j < 8; j++) { qf[j] = (float)q8[j]; kf[j] = (float)k8[j]; }
            if (dl < 32) {
#pragma unroll
                for (int p = 0; p < 4; p++) {
                    const int fi = dl / 2 + p;                   // pair 0..15
                    float freq = exp2f(-(float)fi * 0.830482024f); // 10000^(-fi/16)
                    float ang  = (float)t * freq;
                    float s, c;
                    __sincosf(ang, &s, &c);
                    float a = qf[2 * p], bb = qf[2 * p + 1];
                    qf[2 * p]     = a * c - bb * s;
                    qf[2 * p + 1] = bb * c + a * s;
                    a = kf[2 * p]; bb = kf[2 * p + 1];
                    kf[2 * p]     = a * c - bb * s;
                    kf[2 * p + 1] = bb * c + a * s;
                }
            }
            bf16x8 qo, ko;
#pragma unroll
            for (int j = 0; j < 8; j++) { qo[j] = (bf16)qf[j]; ko[j] = (bf16)kf[j]; }
            *(bf16x8*)&sQ[t * 72 + dl] = qo;
            *(bf16x8*)&sK[t * 72 + dl] = ko;
#pragma unroll
            for (int j = 0; j < 8; j++) sVt[(dl + j) * 40 + t] = v8[j];
        }
    }
    __syncthreads();

    const int fr = lane & 15;
    const int fq = lane >> 4;            // 0..3
    const int mt = wv;                   // this wave's query-row half

    // ---- S = Q K^T for own 16 rows: 1x2 tiles, K=64 ----
    f32x4 S[2];
    S[0] = (f32x4){0.f, 0.f, 0.f, 0.f};
    S[1] = (f32x4){0.f, 0.f, 0.f, 0.f};

    bf16x8 kb0[2], kb1[2];
#pragma unroll
    for (int nt = 0; nt < 2; nt++) {
        kb0[nt] = *(const bf16x8*)&sK[(nt * 16 + fr) * 72 + fq * 8];
        kb1[nt] = *(const bf16x8*)&sK[(nt * 16 + fr) * 72 + 32 + fq * 8];
    }
    {
        bf16x8 a0 = *(const bf16x8*)&sQ[(mt * 16 + fr) * 72 + fq * 8];
        bf16x8 a1 = *(const bf16x8*)&sQ[(mt * 16 + fr) * 72 + 32 + fq * 8];
#pragma unroll
        for (int nt = 0; nt < 2; nt++) {
            S[nt] = __builtin_amdgcn_mfma_f32_16x16x32_bf16(a0, kb0[nt], S[nt], 0, 0, 0);
            S[nt] = __builtin_amdgcn_mfma_f32_16x16x32_bf16(a1, kb1[nt], S[nt], 0, 0, 0);
        }
    }

    // ---- causal softmax in registers ----
    // C-layout: row = mt*16 + fq*4 + r (query t), col = nt*16 + fr (key t)
    float P[2][4];
#pragma unroll
    for (int r = 0; r < 4; r++) {
        const int row = mt * 16 + fq * 4 + r;
        float s0 = S[0][r] * 0.125f;
        float s1 = S[1][r] * 0.125f;
        if (fr > row)      s0 = -1e30f;
        if (16 + fr > row) s1 = -1e30f;
        float mx = fmaxf(s0, s1);
#pragma unroll
        for (int mk = 1; mk <= 8; mk <<= 1) mx = fmaxf(mx, __shfl_xor(mx, mk, 64));
        float e0 = __expf(s0 - mx);
        float e1 = __expf(s1 - mx);
        float sm = e0 + e1;
#pragma unroll
        for (int mk = 1; mk <= 8; mk <<= 1) sm += __shfl_xor(sm, mk, 64);
        float inv = 1.0f / sm;
        P[0][r] = e0 * inv;
        P[1][r] = e1 * inv;
    }

    // ---- barrier: both waves done reading sQ before P overwrites it ----
    __syncthreads();
    bf16* const sP = sQ;                 // alias: P [32][40] over dead Q

    // P scatter (C-layout) into own-wave rows; read back in A-layout.
    // Rows mt*16 .. mt*16+15 are written and read only by this wave -> the
    // LDS write->read ordering is wave-internal (compiler lgkmcnt), no barrier.
#pragma unroll
    for (int nt = 0; nt < 2; nt++)
#pragma unroll
        for (int r = 0; r < 4; r++)
            sP[(mt * 16 + fq * 4 + r) * 40 + nt * 16 + fr] = (bf16)P[nt][r];

    // ---- O = P V for own 16 rows: 1x4 tiles, K=32 ----
    f32x4 O[4];
#pragma unroll
    for (int dt = 0; dt < 4; dt++) O[dt] = (f32x4){0.f, 0.f, 0.f, 0.f};
    {
        bf16x8 a = *(const bf16x8*)&sP[(mt * 16 + fr) * 40 + fq * 8];
#pragma unroll
        for (int dt = 0; dt < 4; dt++) {
            bf16x8 bvv = *(const bf16x8*)&sVt[(dt * 16 + fr) * 40 + fq * 8];
            O[dt] = __builtin_amdgcn_mfma_f32_16x16x32_bf16(a, bvv, O[dt], 0, 0, 0);
        }
    }

    // ---- write O: row t = mt*16+fq*4+r, col d = dt*16+fr ----
#pragma unroll
    for (int dt = 0; dt < 4; dt++)
#pragma unroll
        for (int r = 0; r < 4; r++) {
            const int t = mt * 16 + fq * 4 + r;
            const int d = dt * 16 + fr;
            o[(size_t)(m0 + t * T_STRIDE) * DIM + head * 64 + d] = (bf16)O[dt][r];
        }
}

// ---------------------------------------------------------------------------
extern "C" void kernel_launch(void* const* d_in, const int* in_sizes, int n_in,
                              void* d_out, int out_size, void* d_ws, size_t ws_size,
                              hipStream_t stream) {
    const float* x     = (const float*)d_in[0];
    const float* w_qkv = (const float*)d_in[1];
    const float* w_out = (const float*)d_in[2];
    const float* b_out = (const float*)d_in[3];

    char* ws = (char*)d_ws;
    // workspace layout (bytes)
    bf16* x_b    = (bf16*)(ws + 0);            //  75,497,472  x as bf16
    bf16* wqkv_b = (bf16*)(ws + 75497472);     //   6,291,456
    bf16* wout_b = (bf16*)(ws + 81788928);     //   2,097,152
    bf16* qkv_b  = (bf16*)(ws + 83886080);     // 226,492,416  qkv [M,3072] bf16
    bf16* o_b    = (bf16*)(ws + 310378496);    //  75,497,472  o   [M,1024] bf16
                                               // total 385,875,968

    // convert inputs to bf16
    taa_cvt_bf16<<<(M_TOT * DIM / 4 + 255) / 256, 256, 0, stream>>>(x, x_b, M_TOT * DIM / 4);
    taa_cvt_bf16<<<(E3 * DIM / 4 + 255) / 256, 256, 0, stream>>>(w_qkv, wqkv_b, E3 * DIM / 4);
    taa_cvt_bf16<<<(DIM * DIM / 4 + 255) / 256, 256, 0, stream>>>(w_out, wout_b, DIM * DIM / 4);

    // QKV projection: [36864,3072] = x_b[36864,1024] * wqkv_b[3072,1024]^T
    taa_gemm256<true><<<dim3((M_TOT / 256) * (E3 / 256)), 512, 0, stream>>>(
        x_b, wqkv_b, (void*)qkv_b, nullptr, E3);

    // MFMA attention: one 2-wave block per (n, head)
    taa_attn_mfma<<<1152 * 16, 128, 0, stream>>>(qkv_b, o_b);

    // output projection: d_out[36864,1024] = o_b * wout_b^T + b_out
    taa_gemm256<false><<<dim3((M_TOT / 256) * (DIM / 256)), 512, 0, stream>>>(
        o_b, wout_b, d_out, b_out, DIM);
}

// Round 7
// 674.050 us; speedup vs baseline: 1.0368x; 1.0312x over previous
//
#include <hip/hip_runtime.h>
#include <cstdint>
#include <cstddef>

typedef __bf16 bf16;
typedef __attribute__((ext_vector_type(8))) bf16  bf16x8;
typedef __attribute__((ext_vector_type(4))) bf16  bf16x4;
typedef __attribute__((ext_vector_type(4))) float f32x4;

// Problem constants
#define B_SZ   2
#define T_SZ   32
#define H_SZ   18
#define W_SZ   32
#define DIM    1024
#define NHEAD  16
#define HDIM   64
#define E3     3072                  // 3*NHEAD*HDIM
#define M_TOT  36864                 // B*T*H*W
#define N_SP   1152                  // B*H*W spatial positions (b*576 + h*32 + w)
#define GK     1024                  // K of both GEMMs (compile-time)
#define NKT    16                    // GK / 64
#define HPANEL 2359296               // N_SP * T_SZ * HDIM  (one [head] panel, elems)

// qkv workspace layout (attention-native): [sel*16+head][n][t][d], elem addr =
//   (sel*16+head)*HPANEL + n*2048 + t*64 + d
// o workspace layout: row-major [n*32+t][DIM] (permuted rows; out-proj GEMM
//   runs over permuted rows and its epilogue scatters back to original m).

// ---------------------------------------------------------------------------
// fp32 -> bf16 conversion (vectorized x4)
// ---------------------------------------------------------------------------
__global__ void taa_cvt_bf16(const float* __restrict__ s, bf16* __restrict__ d, int n4) {
    int i = blockIdx.x * 256 + threadIdx.x;
    if (i >= n4) return;
    float4 v = ((const float4*)s)[i];
    bf16x4 o;
    o.x = (bf16)v.x; o.y = (bf16)v.y; o.z = (bf16)v.z; o.w = (bf16)v.w;
    ((bf16x4*)d)[i] = o;
}

// ---------------------------------------------------------------------------
// async global->LDS 16B (wave-uniform base + lane*16 semantics)
// ---------------------------------------------------------------------------
__device__ __forceinline__ void async_copy_16(const bf16* g, bf16* l) {
    __builtin_amdgcn_global_load_lds((__attribute__((address_space(1))) void*)g,
                                     (__attribute__((address_space(3))) void*)l,
                                     16, 0, 0);
}

#define MFMA16(a, b, c) __builtin_amdgcn_mfma_f32_16x16x32_bf16((a), (b), (c), 0, 0, 0)

// ---------------------------------------------------------------------------
// C = A[M,K] * B[N,K]^T, bf16 in, fp32 accumulate. 256x256 tile, BK=64,
// 512 threads = 8 waves (2M x 4N), each wave 128x64 output.
// K-loop: round-5 schedule (equal-best 262us / 37% MfmaUtil): stage kt+1 ->
// buf^1 at tile start; 24 ds_reads + 64 MFMA streamed; lgkmcnt(0)+vmcnt(0)+
// one barrier at tile end. T2 chunk-XOR swizzle; XCD-aware block swizzle.
//
// Epilogues (round-7): OUT_BF16 (QKV) writes attention-native layout
// [sel*16+head][n][t][d]; wave cols are 64-aligned => one head per wave.
// f32 (out-proj) consumes permuted rows m' = n*32+t and scatters back to
// original m = b*18432 + t*576 + sp. Same arithmetic, same store widths.
// ---------------------------------------------------------------------------
template<bool OUT_BF16>
__global__ __launch_bounds__(512, 2)
void taa_gemm256(const bf16* __restrict__ A, const bf16* __restrict__ Bm,
                 void* __restrict__ Cout, const float* __restrict__ bias, int N) {
    __shared__ __align__(16) bf16 sA[2][2][8192];   // [buf][half][128*64]
    __shared__ __align__(16) bf16 sB[2][2][8192];

    const int tid  = threadIdx.x;
    const int lane = tid & 63;
    const int wv   = tid >> 6;          // 0..7
    const int wm   = wv >> 2;           // 0..1 : wave rows  wm*128
    const int wn   = wv & 3;            // 0..3 : wave cols  wn*64
    const int fr   = lane & 15;
    const int fq   = lane >> 4;

    // XCD-aware bijective swizzle (nwg % 8 == 0 guaranteed by launch)
    const int ntn = N >> 8;
    const int nwg = gridDim.x;
    const int bid = blockIdx.x;
    const int swz = (bid & 7) * (nwg >> 3) + (bid >> 3);
    const int bm  = (swz / ntn) << 8;
    const int bn  = (swz % ntn) << 8;

    // staging: linear LDS dest, pre-swizzled global source chunk
    const int srow = tid >> 3;                          // 0..63
    const int scol = ((tid & 7) ^ (srow & 7)) << 3;     // element col in [0,64)
    const bf16* gA0 = A  + (size_t)(bm + srow) * GK + scol;
    const bf16* gB0 = Bm + (size_t)(bn + srow) * GK + scol;

    // per-lane swizzled k-chunk byte offsets for fragment ds_reads
    const int swx = (fr & 7) << 4;
    const int cs0 = (fq * 16) ^ swx;          // k-step 0
    const int cs1 = (64 + fq * 16) ^ swx;     // k-step 1

    f32x4 acc[2][2][4][2];                    // [ms][ns][i][j]
#pragma unroll
    for (int ms = 0; ms < 2; ms++)
#pragma unroll
        for (int ns = 0; ns < 2; ns++)
#pragma unroll
            for (int i = 0; i < 4; i++)
#pragma unroll
                for (int j = 0; j < 2; j++)
                    acc[ms][ns][i][j] = (f32x4){0.f, 0.f, 0.f, 0.f};

    auto stage = [&](const bf16* g0, bf16* lbase, int h, int kt) {
        const bf16* g = g0 + (size_t)(h * 128) * GK + kt * 64;
        async_copy_16(g,                    lbase + h * 8192 + tid * 8);
        async_copy_16(g + (size_t)64 * GK,  lbase + h * 8192 + 4096 + tid * 8);
    };

    // ---- prologue: stage kt=0 -> buf0, drain, sync ----
    stage(gB0, &sB[0][0][0], 0, 0); stage(gB0, &sB[0][0][0], 1, 0);
    stage(gA0, &sA[0][0][0], 0, 0); stage(gA0, &sA[0][0][0], 1, 0);
    asm volatile("s_waitcnt vmcnt(0)" ::: "memory");
    __builtin_amdgcn_s_barrier();
    asm volatile("" ::: "memory");

#pragma unroll 2
    for (int kt = 0; kt < NKT; ++kt) {
        const int buf = kt & 1;
        const char* ab = (const char*)&sA[buf][wm][0] + fr * 128;
        const char* bb = (const char*)&sB[buf][wn >> 1][0] + ((wn & 1) * 64 + fr) * 128;

        if (kt + 1 < NKT) {
            stage(gB0, &sB[buf ^ 1][0][0], 0, kt + 1);
            stage(gB0, &sB[buf ^ 1][0][0], 1, kt + 1);
            stage(gA0, &sA[buf ^ 1][0][0], 0, kt + 1);
            stage(gA0, &sA[buf ^ 1][0][0], 1, kt + 1);
        }

        bf16x8 af[4][2];    // A half ms=0
        bf16x8 ag[4][2];    // A half ms=1
        bf16x8 bf0[2][2];   // B ns=0
        bf16x8 bf1[2][2];   // B ns=1

        af[0][0] = *(const bf16x8*)(ab + cs0);
        af[0][1] = *(const bf16x8*)(ab + cs1);
#pragma unroll
        for (int j = 0; j < 2; j++) {
            bf0[j][0] = *(const bf16x8*)(bb + j * 2048 + cs0);
            bf0[j][1] = *(const bf16x8*)(bb + j * 2048 + cs1);
        }
#pragma unroll
        for (int i = 1; i < 4; i++) {
            af[i][0] = *(const bf16x8*)(ab + i * 2048 + cs0);
            af[i][1] = *(const bf16x8*)(ab + i * 2048 + cs1);
        }
#pragma unroll
        for (int j = 0; j < 2; j++) {
            bf1[j][0] = *(const bf16x8*)(bb + 4096 + j * 2048 + cs0);
            bf1[j][1] = *(const bf16x8*)(bb + 4096 + j * 2048 + cs1);
        }
#pragma unroll
        for (int i = 0; i < 4; i++) {
            ag[i][0] = *(const bf16x8*)(ab + 8192 + i * 2048 + cs0);
            ag[i][1] = *(const bf16x8*)(ab + 8192 + i * 2048 + cs1);
        }

        __builtin_amdgcn_s_setprio(1);
#pragma unroll
        for (int i = 0; i < 4; i++)
#pragma unroll
            for (int j = 0; j < 2; j++) {
                acc[0][0][i][j] = MFMA16(af[i][0], bf0[j][0], acc[0][0][i][j]);
                acc[0][0][i][j] = MFMA16(af[i][1], bf0[j][1], acc[0][0][i][j]);
            }
#pragma unroll
        for (int i = 0; i < 4; i++)
#pragma unroll
            for (int j = 0; j < 2; j++) {
                acc[0][1][i][j] = MFMA16(af[i][0], bf1[j][0], acc[0][1][i][j]);
                acc[0][1][i][j] = MFMA16(af[i][1], bf1[j][1], acc[0][1][i][j]);
            }
#pragma unroll
        for (int i = 0; i < 4; i++)
#pragma unroll
            for (int j = 0; j < 2; j++) {
                acc[1][1][i][j] = MFMA16(ag[i][0], bf1[j][0], acc[1][1][i][j]);
                acc[1][1][i][j] = MFMA16(ag[i][1], bf1[j][1], acc[1][1][i][j]);
            }
#pragma unroll
        for (int i = 0; i < 4; i++)
#pragma unroll
            for (int j = 0; j < 2; j++) {
                acc[1][0][i][j] = MFMA16(ag[i][0], bf0[j][0], acc[1][0][i][j]);
                acc[1][0][i][j] = MFMA16(ag[i][1], bf0[j][1], acc[1][0][i][j]);
            }
        __builtin_amdgcn_s_setprio(0);

        asm volatile("s_waitcnt lgkmcnt(0) vmcnt(0)" ::: "memory");
        __builtin_amdgcn_s_barrier();
        asm volatile("" ::: "memory");
    }

    // ---- epilogues: C/D layout col=lane&15, row=(lane>>4)*4+reg ----
    if constexpr (OUT_BF16) {
        // QKV: write attention-native layout [sel*16+head][n][t][d].
        // wave cols = [colb, colb+64) = exactly one head (colb 64-aligned);
        // d = ns*32 + j*16 + fr.
        bf16* C = (bf16*)Cout;
        const int sh = (bn + wn * 64) >> 6;          // sel*16 + head (wave-uniform)
        bf16* Cw = C + (size_t)sh * HPANEL;
#pragma unroll
        for (int ms = 0; ms < 2; ms++)
#pragma unroll
            for (int i = 0; i < 4; i++)
#pragma unroll
                for (int r = 0; r < 4; r++) {
                    const int m   = bm + wm * 128 + ms * 64 + i * 16 + fq * 4 + r;
                    const int b   = m / 18432;
                    const int rem = m - b * 18432;
                    const int t   = rem / 576;
                    const int sp  = rem - t * 576;
                    const size_t ro = (size_t)(b * 576 + sp) * 2048 + t * 64 + fr;
#pragma unroll
                    for (int ns = 0; ns < 2; ns++)
#pragma unroll
                        for (int j = 0; j < 2; j++)
                            Cw[ro + ns * 32 + j * 16] = (bf16)acc[ms][ns][i][j][r];
                }
    } else {
        // out-proj: A rows were permuted m' = n*32 + t; scatter back to
        // original m = b*18432 + t*576 + sp for the final output.
        float* C = (float*)Cout;
#pragma unroll
        for (int ms = 0; ms < 2; ms++)
#pragma unroll
            for (int i = 0; i < 4; i++)
#pragma unroll
                for (int r = 0; r < 4; r++) {
                    const int mp = bm + wm * 128 + ms * 64 + i * 16 + fq * 4 + r;
                    const int nn = mp >> 5;          // n = b*576 + sp
                    const int t  = mp & 31;
                    const int b  = nn / 576;
                    const int sp = nn - b * 576;
                    const size_t mo = (size_t)b * 18432 + (size_t)t * 576 + sp;
#pragma unroll
                    for (int ns = 0; ns < 2; ns++)
#pragma unroll
                        for (int j = 0; j < 2; j++) {
                            const int col = bn + wn * 64 + ns * 32 + j * 16 + fr;
                            C[mo * DIM + col] = acc[ms][ns][i][j][r] + bias[col];
                        }
                }
    }
}

// ---------------------------------------------------------------------------
// MFMA attention, round-7: qkv is attention-native [sel*16+head][n][t][d] ->
// each block's Q/K/V panels are 4KB CONTIGUOUS (wave load = 2KB contiguous,
// vs 96 scattered 128B transactions before). o written as [n*32+t][DIM] via
// wave-local LDS bounce -> 16B stores, 128B contiguous per 4 lanes.
// 2 waves per block (128 threads); wave wv owns query rows wv*16..wv*16+15.
// LDS 14.3KB; sP aliases dead sQ, O-bounce aliases dead sK.
// ---------------------------------------------------------------------------
__global__ __launch_bounds__(128)
void taa_attn_mfma(const bf16* __restrict__ qkv, bf16* __restrict__ o) {
    __shared__ __align__(16) bf16 sQ[32 * 72];   // aliased as sP [32][40] later
    __shared__ __align__(16) bf16 sK[32 * 72];   // aliased as O-bounce later
    __shared__ __align__(16) bf16 sVt[64 * 40];  // V^T [d][t], stride 40

    const int tid  = threadIdx.x;
    const int lane = tid & 63;
    const int wv   = tid >> 6;          // 0..1 : query-row half (mt)
    const int bid  = blockIdx.x;        // n*16 + head
    const int head = bid & 15;
    const int n    = bid >> 4;          // 0..1151 = b*576 + h*32 + w

    const bf16* qb = qkv + ((size_t)head        * N_SP + n) * 2048;
    const bf16* kb = qkv + ((size_t)(16 + head) * N_SP + n) * 2048;
    const bf16* vb = qkv + ((size_t)(32 + head) * N_SP + n) * 2048;

    // ---- cooperative contiguous load of Q,K (RoPE) and V (transposed) ----
    {
        const int t  = tid >> 2;          // 0..31
        const int d0 = (tid & 3) << 4;    // 0,16,32,48
        const int off = t * 64 + d0;
        bf16x8 q8a = *(const bf16x8*)(qb + off);
        bf16x8 q8b = *(const bf16x8*)(qb + off + 8);
        bf16x8 k8a = *(const bf16x8*)(kb + off);
        bf16x8 k8b = *(const bf16x8*)(kb + off + 8);
        bf16x8 v8a = *(const bf16x8*)(vb + off);
        bf16x8 v8b = *(const bf16x8*)(vb + off + 8);
        if (d0 < 32) {                    // rotate pairs (d, d+1), d < 32
            float qf[16], kf[16];
#pragma unroll
            for (int j = 0; j < 8; j++) {
                qf[j] = (float)q8a[j]; qf[8 + j] = (float)q8b[j];
                kf[j] = (float)k8a[j]; kf[8 + j] = (float)k8b[j];
            }
#pragma unroll
            for (int p = 0; p < 8; p++) {
                const int fi = (d0 >> 1) + p;                  // pair index 0..15
                float freq = exp2f(-(float)fi * 0.830482024f); // 10000^(-fi/16)
                float ang  = (float)t * freq;
                float s, c;
                __sincosf(ang, &s, &c);
                float a = qf[2 * p], bb2 = qf[2 * p + 1];
                qf[2 * p]     = a * c - bb2 * s;
                qf[2 * p + 1] = bb2 * c + a * s;
                a = kf[2 * p]; bb2 = kf[2 * p + 1];
                kf[2 * p]     = a * c - bb2 * s;
                kf[2 * p + 1] = bb2 * c + a * s;
            }
#pragma unroll
            for (int j = 0; j < 8; j++) {
                q8a[j] = (bf16)qf[j]; q8b[j] = (bf16)qf[8 + j];
                k8a[j] = (bf16)kf[j]; k8b[j] = (bf16)kf[8 + j];
            }
        }
        *(bf16x8*)&sQ[t * 72 + d0]     = q8a;
        *(bf16x8*)&sQ[t * 72 + d0 + 8] = q8b;
        *(bf16x8*)&sK[t * 72 + d0]     = k8a;
        *(bf16x8*)&sK[t * 72 + d0 + 8] = k8b;
#pragma unroll
        for (int j = 0; j < 8; j++) {
            sVt[(d0 + j) * 40 + t]     = v8a[j];
            sVt[(d0 + 8 + j) * 40 + t] = v8b[j];
        }
    }
    __syncthreads();

    const int fr = lane & 15;
    const int fq = lane >> 4;            // 0..3
    const int mt = wv;                   // this wave's query-row half

    // ---- S = Q K^T for own 16 rows: 1x2 tiles, K=64 ----
    f32x4 S[2];
    S[0] = (f32x4){0.f, 0.f, 0.f, 0.f};
    S[1] = (f32x4){0.f, 0.f, 0.f, 0.f};

    bf16x8 kb0[2], kb1[2];
#pragma unroll
    for (int nt = 0; nt < 2; nt++) {
        kb0[nt] = *(const bf16x8*)&sK[(nt * 16 + fr) * 72 + fq * 8];
        kb1[nt] = *(const bf16x8*)&sK[(nt * 16 + fr) * 72 + 32 + fq * 8];
    }
    {
        bf16x8 a0 = *(const bf16x8*)&sQ[(mt * 16 + fr) * 72 + fq * 8];
        bf16x8 a1 = *(const bf16x8*)&sQ[(mt * 16 + fr) * 72 + 32 + fq * 8];
#pragma unroll
        for (int nt = 0; nt < 2; nt++) {
            S[nt] = __builtin_amdgcn_mfma_f32_16x16x32_bf16(a0, kb0[nt], S[nt], 0, 0, 0);
            S[nt] = __builtin_amdgcn_mfma_f32_16x16x32_bf16(a1, kb1[nt], S[nt], 0, 0, 0);
        }
    }

    // ---- causal softmax in registers ----
    // C-layout: row = mt*16 + fq*4 + r (query t), col = nt*16 + fr (key t)
    float P[2][4];
#pragma unroll
    for (int r = 0; r < 4; r++) {
        const int row = mt * 16 + fq * 4 + r;
        float s0 = S[0][r] * 0.125f;
        float s1 = S[1][r] * 0.125f;
        if (fr > row)      s0 = -1e30f;
        if (16 + fr > row) s1 = -1e30f;
        float mx = fmaxf(s0, s1);
#pragma unroll
        for (int mk = 1; mk <= 8; mk <<= 1) mx = fmaxf(mx, __shfl_xor(mx, mk, 64));
        float e0 = __expf(s0 - mx);
        float e1 = __expf(s1 - mx);
        float sm = e0 + e1;
#pragma unroll
        for (int mk = 1; mk <= 8; mk <<= 1) sm += __shfl_xor(sm, mk, 64);
        float inv = 1.0f / sm;
        P[0][r] = e0 * inv;
        P[1][r] = e1 * inv;
    }

    // ---- barrier: both waves done reading sQ/sK before aliasing ----
    __syncthreads();
    bf16* const sP = sQ;                 // alias: P [32][40] over dead Q

    // P scatter (C-layout) into own-wave rows; read back in A-layout.
#pragma unroll
    for (int nt = 0; nt < 2; nt++)
#pragma unroll
        for (int r = 0; r < 4; r++)
            sP[(mt * 16 + fq * 4 + r) * 40 + nt * 16 + fr] = (bf16)P[nt][r];

    // ---- O = P V for own 16 rows: 1x4 tiles, K=32 ----
    f32x4 O[4];
#pragma unroll
    for (int dt = 0; dt < 4; dt++) O[dt] = (f32x4){0.f, 0.f, 0.f, 0.f};
    {
        bf16x8 a = *(const bf16x8*)&sP[(mt * 16 + fr) * 40 + fq * 8];
#pragma unroll
        for (int dt = 0; dt < 4; dt++) {
            bf16x8 bvv = *(const bf16x8*)&sVt[(dt * 16 + fr) * 40 + fq * 8];
            O[dt] = __builtin_amdgcn_mfma_f32_16x16x32_bf16(a, bvv, O[dt], 0, 0, 0);
        }
    }

    // ---- O write via wave-local LDS bounce (dead sK) -> 16B stores ----
    // o layout: [n*32 + t][DIM], col = head*64 + d.
#pragma unroll
    for (int dt = 0; dt < 4; dt++)
#pragma unroll
        for (int r = 0; r < 4; r++)
            sK[(mt * 16 + fq * 4 + r) * 72 + dt * 16 + fr] = (bf16)O[dt][r];

    const int tr = mt * 16 + (lane >> 2);     // wave-local row
    const int c0 = (lane & 3) << 4;           // 0,16,32,48
    bf16x8 o0 = *(const bf16x8*)&sK[tr * 72 + c0];
    bf16x8 o1 = *(const bf16x8*)&sK[tr * 72 + c0 + 8];
    bf16* ob = o + ((size_t)n * 32 + tr) * DIM + head * 64 + c0;
    *(bf16x8*)(ob)     = o0;
    *(bf16x8*)(ob + 8) = o1;
}

// ---------------------------------------------------------------------------
extern "C" void kernel_launch(void* const* d_in, const int* in_sizes, int n_in,
                              void* d_out, int out_size, void* d_ws, size_t ws_size,
                              hipStream_t stream) {
    const float* x     = (const float*)d_in[0];
    const float* w_qkv = (const float*)d_in[1];
    const float* w_out = (const float*)d_in[2];
    const float* b_out = (const float*)d_in[3];

    char* ws = (char*)d_ws;
    // workspace layout (bytes)
    bf16* x_b    = (bf16*)(ws + 0);            //  75,497,472  x as bf16
    bf16* wqkv_b = (bf16*)(ws + 75497472);     //   6,291,456
    bf16* wout_b = (bf16*)(ws + 81788928);     //   2,097,152
    bf16* qkv_b  = (bf16*)(ws + 83886080);     // 226,492,416  qkv [48][1152][32][64] bf16
    bf16* o_b    = (bf16*)(ws + 310378496);    //  75,497,472  o   [36864][1024] bf16 (perm rows)
                                               // total 385,875,968

    // convert inputs to bf16
    taa_cvt_bf16<<<(M_TOT * DIM / 4 + 255) / 256, 256, 0, stream>>>(x, x_b, M_TOT * DIM / 4);
    taa_cvt_bf16<<<(E3 * DIM / 4 + 255) / 256, 256, 0, stream>>>(w_qkv, wqkv_b, E3 * DIM / 4);
    taa_cvt_bf16<<<(DIM * DIM / 4 + 255) / 256, 256, 0, stream>>>(w_out, wout_b, DIM * DIM / 4);

    // QKV projection (epilogue writes attention-native layout)
    taa_gemm256<true><<<dim3((M_TOT / 256) * (E3 / 256)), 512, 0, stream>>>(
        x_b, wqkv_b, (void*)qkv_b, nullptr, E3);

    // MFMA attention: one 2-wave block per (n, head); contiguous panel reads
    taa_attn_mfma<<<N_SP * NHEAD, 128, 0, stream>>>(qkv_b, o_b);

    // output projection over permuted rows; epilogue scatters to original m
    taa_gemm256<false><<<dim3((M_TOT / 256) * (DIM / 256)), 512, 0, stream>>>(
        o_b, wout_b, d_out, b_out, DIM);
}